// Round 2
// 687.439 us; speedup vs baseline: 1.0451x; 1.0451x over previous
//
#include <hip/hip_runtime.h>

#define BB 32
#define SS 4096
#define DD 1024
#define OO 1024
#define KK 2048
#define RAD 64
#define NSPLIT 8
#define NBLK (SS / 16)  // k_score blocks per batch = 256

typedef float f4 __attribute__((ext_vector_type(4)));

__device__ __forceinline__ float dot4(f4 a, f4 q) {
  return a.x * q.x + a.y * q.y + a.z * q.z + a.w * q.w;
}

// ---- Kernel 1: score[b,s] = dot(src[b,s,:], tgt[b,:]) + fused block softmax partials ----
// grid (S/16, B), 256 threads = 4 waves, 4 s per wave. All 16 KB of a wave's
// src loads are issued before any arithmetic (max MLP); 4 independent dot
// partials per row; the 4 rows' butterfly reduces are interleaved (6 dependent
// steps total). Epilogue computes per-block (max, sum-exp) partials so the
// old full-score k_stats pass disappears.
__global__ __launch_bounds__(256) void k_score(const float* __restrict__ src,
                                               const float* __restrict__ tgt,
                                               float* __restrict__ score,
                                               float* __restrict__ blkstats) {
  const int b = blockIdx.y;
  const int wave = threadIdx.x >> 6;
  const int lane = threadIdx.x & 63;
  const int s_base = blockIdx.x * 16 + wave * 4;

  const f4* tv = (const f4*)(tgt + (size_t)b * DD);
  f4 q0 = tv[lane], q1 = tv[64 + lane], q2 = tv[128 + lane], q3 = tv[192 + lane];

  const f4* r0 = (const f4*)(src + ((size_t)b * SS + s_base) * DD) + lane;
  const f4* r1 = r0 + 256;  // row stride = DD/4 f4
  const f4* r2 = r0 + 512;
  const f4* r3 = r0 + 768;

  // Issue all 16 loads up front — nontemporal: pure stream, no reuse worth caching.
  f4 a00 = __builtin_nontemporal_load(r0);
  f4 a01 = __builtin_nontemporal_load(r0 + 64);
  f4 a02 = __builtin_nontemporal_load(r0 + 128);
  f4 a03 = __builtin_nontemporal_load(r0 + 192);
  f4 a10 = __builtin_nontemporal_load(r1);
  f4 a11 = __builtin_nontemporal_load(r1 + 64);
  f4 a12 = __builtin_nontemporal_load(r1 + 128);
  f4 a13 = __builtin_nontemporal_load(r1 + 192);
  f4 a20 = __builtin_nontemporal_load(r2);
  f4 a21 = __builtin_nontemporal_load(r2 + 64);
  f4 a22 = __builtin_nontemporal_load(r2 + 128);
  f4 a23 = __builtin_nontemporal_load(r2 + 192);
  f4 a30 = __builtin_nontemporal_load(r3);
  f4 a31 = __builtin_nontemporal_load(r3 + 64);
  f4 a32 = __builtin_nontemporal_load(r3 + 128);
  f4 a33 = __builtin_nontemporal_load(r3 + 192);

  // 4 independent partials per row, pairwise combine (breaks serial FMA chain).
  float p0 = (dot4(a00, q0) + dot4(a01, q1)) + (dot4(a02, q2) + dot4(a03, q3));
  float p1 = (dot4(a10, q0) + dot4(a11, q1)) + (dot4(a12, q2) + dot4(a13, q3));
  float p2 = (dot4(a20, q0) + dot4(a21, q1)) + (dot4(a22, q2) + dot4(a23, q3));
  float p3 = (dot4(a30, q0) + dot4(a31, q1)) + (dot4(a32, q2) + dot4(a33, q3));

  // Interleaved butterflies: 6 dependent steps, 4 independent shuffles each.
  for (int off = 32; off > 0; off >>= 1) {
    p0 += __shfl_xor(p0, off);
    p1 += __shfl_xor(p1, off);
    p2 += __shfl_xor(p2, off);
    p3 += __shfl_xor(p3, off);
  }

  float sel = (lane == 0) ? p0 : ((lane == 1) ? p1 : ((lane == 2) ? p2 : p3));
  if (lane < 4) score[(size_t)b * SS + s_base + lane] = sel;

  // Fused per-block softmax partials over the block's 16 rows.
  __shared__ float rowv[16];
  if (lane < 4) rowv[wave * 4 + lane] = sel;
  __syncthreads();
  if (threadIdx.x == 0) {
    float m = rowv[0];
    #pragma unroll
    for (int i = 1; i < 16; ++i) m = fmaxf(m, rowv[i]);
    float l = 0.f;
    #pragma unroll
    for (int i = 0; i < 16; ++i) l += expf(rowv[i] - m);
    float* bs = blkstats + ((size_t)b * NBLK + blockIdx.x) * 2;
    bs[0] = m; bs[1] = l;
  }
}

// ---- Kernel 2: combine 256 per-block (m,l) partials per batch -> stats[b] ----
__global__ __launch_bounds__(256) void k_combine(const float* __restrict__ blkstats,
                                                 float* __restrict__ stats) {
  const int b = blockIdx.x;
  const int wave = threadIdx.x >> 6;
  const int lane = threadIdx.x & 63;
  const float* bs = blkstats + ((size_t)b * NBLK + threadIdx.x) * 2;
  float m = bs[0];
  float l = bs[1];
  for (int off = 32; off > 0; off >>= 1) {
    float m2 = __shfl_xor(m, off);
    float l2 = __shfl_xor(l, off);
    float mm = fmaxf(m, m2);
    l = l * expf(m - mm) + l2 * expf(m2 - mm);
    m = mm;
  }
  __shared__ float sm[4], sl[4];
  if (lane == 0) { sm[wave] = m; sl[wave] = l; }
  __syncthreads();
  if (threadIdx.x == 0) {
    float M = fmaxf(fmaxf(sm[0], sm[1]), fmaxf(sm[2], sm[3]));
    float L = sl[0] * expf(sm[0] - M) + sl[1] * expf(sm[1] - M) +
              sl[2] * expf(sm[2] - M) + sl[3] * expf(sm[3] - M);
    stats[2 * b] = M;
    stats[2 * b + 1] = L;
  }
}

// ---- Kernel 3: windowed weighted sum ----
// pos_w = exp(-rel^2/128) < 1e-14 beyond |rel|=64 -> window [pos-64, pos+64].
__global__ __launch_bounds__(256) void k_weighted(const float* __restrict__ src,
                                                  const float* __restrict__ score,
                                                  const float* __restrict__ stats,
                                                  const int* __restrict__ pos,
                                                  float* __restrict__ partial) {
  const int b = blockIdx.y;
  const int split = blockIdx.x;
  const int p = pos[b];
  int w0 = p - RAD; if (w0 < 0) w0 = 0;
  int w1 = p + RAD + 1; if (w1 > SS) w1 = SS;
  const int len = w1 - w0;
  const int chunk = (len + NSPLIT - 1) / NSPLIT;
  int cs = w0 + split * chunk;
  int ce = cs + chunk; if (ce > w1) ce = w1;
  const float m = stats[2 * b];
  const float inv = 1.f / stats[2 * b + 1];
  const int t = threadIdx.x;
  float a0 = 0.f, a1 = 0.f, a2 = 0.f, a3 = 0.f;
  for (int s = cs; s < ce; ++s) {
    float rel = (float)(s - p);
    float w = expf(score[(size_t)b * SS + s] - m) * inv * expf(rel * rel * (-1.f / 128.f));
    f4 v = ((const f4*)(src + ((size_t)b * SS + s) * DD))[t];
    a0 += w * v.x; a1 += w * v.y; a2 += w * v.z; a3 += w * v.w;
  }
  f4* outp = (f4*)(partial + ((size_t)split * BB + b) * DD);
  f4 o; o.x = a0; o.y = a1; o.z = a2; o.w = a3;
  outp[t] = o;  // always write: ws is re-poisoned
}

// ---- Kernel 4: out[b,o] = tanh( [tgt, weighted] @ W ) ----
__global__ __launch_bounds__(256) void k_out(const float* __restrict__ tgt,
                                             const float* __restrict__ partial,
                                             const float* __restrict__ W,
                                             float* __restrict__ out) {
  const int b = blockIdx.y;
  const int o0 = blockIdx.x * 128;
  __shared__ float c[KK];
  __shared__ float red[4][128];
  for (int k = threadIdx.x; k < KK; k += 256) {
    float v;
    if (k < DD) {
      v = tgt[(size_t)b * DD + k];
    } else {
      const int d = k - DD;
      v = 0.f;
      for (int pp = 0; pp < NSPLIT; ++pp) v += partial[((size_t)pp * BB + b) * DD + d];
    }
    c[k] = v;
  }
  __syncthreads();
  const int ks = threadIdx.x >> 6;   // k-quarter
  const int ol = threadIdx.x & 63;   // o-pair lane
  float acc0 = 0.f, acc1 = 0.f;
  const float* wp = W + o0 + ol * 2;
  for (int k = ks * 512; k < ks * 512 + 512; ++k) {
    float2 wv = *(const float2*)(wp + (size_t)k * OO);
    float ck = c[k];
    acc0 += ck * wv.x; acc1 += ck * wv.y;
  }
  red[ks][ol * 2] = acc0;
  red[ks][ol * 2 + 1] = acc1;
  __syncthreads();
  if (threadIdx.x < 128) {
    float s = red[0][threadIdx.x] + red[1][threadIdx.x] + red[2][threadIdx.x] + red[3][threadIdx.x];
    out[(size_t)b * OO + o0 + threadIdx.x] = tanhf(s);
  }
}

extern "C" void kernel_launch(void* const* d_in, const int* in_sizes, int n_in,
                              void* d_out, int out_size, void* d_ws, size_t ws_size,
                              hipStream_t stream) {
  const float* src = (const float*)d_in[0];
  const float* tgt = (const float*)d_in[1];
  const int* pos   = (const int*)d_in[2];
  const float* W   = (const float*)d_in[3];
  float* out = (float*)d_out;

  float* ws       = (float*)d_ws;
  float* score    = ws;                         // B*S          = 131072 floats
  float* stats    = score + (size_t)BB * SS;    // 2*B          = 64 floats
  float* partial  = stats + 2 * BB;             // NSPLIT*B*D   = 262144 floats
  float* blkstats = partial + (size_t)NSPLIT * BB * DD;  // B*NBLK*2 = 16384 floats

  k_score   <<<dim3(SS / 16, BB), 256, 0, stream>>>(src, tgt, score, blkstats);
  k_combine <<<BB,                256, 0, stream>>>(blkstats, stats);
  k_weighted<<<dim3(NSPLIT, BB),  256, 0, stream>>>(src, score, stats, pos, partial);
  k_out     <<<dim3(OO / 128, BB), 256, 0, stream>>>(tgt, partial, W, out);
}